// Round 4
// baseline (1863.288 us; speedup 1.0000x reference)
//
#include <hip/hip_runtime.h>
#include <math.h>

#define EPSF 1.01e-08f

namespace {
constexpr int NB = 4;                 // batch
constexpr int HH = 252, TW = 2048;    // conv1 spatial
constexpr int C1 = 16, DD = 12, FF = 84;
constexpr int LLEN = FF * TW;         // 172032

// workspace layout (float elements)
constexpr size_t OFF_H   = 0;
constexpr size_t SZ_H    = (size_t)NB * C1 * HH * TW;       // 33,030,144
constexpr size_t SZ_QKV  = (size_t)NB * LLEN * DD;          // 8,257,536
constexpr size_t OFF_Q   = OFF_H + SZ_H;
constexpr size_t OFF_K   = OFF_Q + SZ_QKV;
constexpr size_t OFF_V   = OFF_K + SZ_QKV;
constexpr size_t OFF_SI  = OFF_V + SZ_QKV;                  // sink_in  (NB*LLEN)
constexpr size_t OFF_SA  = OFF_SI + (size_t)NB * LLEN;      // sink_alloc
constexpr size_t OFF_WP  = OFF_SA + (size_t)NB * LLEN;      // folded conv1 w (3200)
constexpr size_t OFF_B1  = OFF_WP + 3200;                   // folded conv1 b (16)
constexpr size_t OFF_WQT = OFF_B1 + 16;                     // wq transposed (1728)
constexpr size_t OFF_WKT = OFF_WQT + 1728;                  // wkv transposed (1728)
constexpr size_t FTOT    = OFF_WKT + 1728;
constexpr size_t DBYTE   = FTOT * sizeof(float);            // 8-byte aligned

// f64 accumulator slots (index into double*)
constexpr int DO_MSUM = 0;     // 4
constexpr int DO_KSUM = 4;     // 4*12
constexpr int DO_QSUM = 52;    // 4*12
constexpr int DO_SKQ  = 100;   // 4*12
constexpr int DO_SQS  = 148;   // 4*12
constexpr int DO_SE   = 196;   // 4
constexpr int DO_M    = 200;   // 4*144
constexpr int NDBL    = 776;
}

__device__ __forceinline__ float wsum(float v) {
#pragma unroll
  for (int m = 1; m < 64; m <<= 1) v += __shfl_xor(v, m, 64);
  return v;
}
__device__ __forceinline__ double wsumd(double v) {
#pragma unroll
  for (int m = 1; m < 64; m <<= 1) v += __shfl_xor(v, m, 64);
  return v;
}
__device__ __forceinline__ void atomAddD(double* p, double v) { unsafeAtomicAdd(p, v); }
__device__ __forceinline__ float sigm(float x) { return 1.f / (1.f + expf(-x)); }

// ---------------- weight prep: fold BN into conv1, transpose conv2 weights ----
__global__ void k_prep(const float* __restrict__ w_pre, const float* __restrict__ b_pre,
                       const float* __restrict__ g, const float* __restrict__ be,
                       const float* __restrict__ mean, const float* __restrict__ var,
                       const float* __restrict__ wq, const float* __restrict__ wkv,
                       float* __restrict__ ws) {
  int tid = blockIdx.x * 256 + threadIdx.x;
  int stride = gridDim.x * 256;
  if (tid < 16) {
    float sc = g[tid] / sqrtf(var[tid] + 1e-5f);
    ws[OFF_B1 + tid] = (b_pre[tid] - mean[tid]) * sc + be[tid];
  }
  for (int idx = tid; idx < 3200; idx += stride) {
    int co = idx & 15, r = idx >> 4;     // r = ci*25 + p
    int ci = r / 25, p = r % 25;
    float sc = g[co] / sqrtf(var[co] + 1e-5f);
    ws[OFF_WP + idx] = w_pre[(co * 8 + ci) * 25 + p] * sc;
  }
  for (int idx = tid; idx < 1728; idx += stride) {
    int d = idx % 12, r = idx / 12;      // r = c*9 + p
    ws[OFF_WQT + idx] = wq[d * 144 + r];
    ws[OFF_WKT + idx] = wkv[d * 144 + r];
  }
}

// ---------------- conv1 5x5 same + BN(folded) + LeakyReLU --------------------
// Thread: 8 couts x 4 adjacent cols. blockIdx.z = b*2 + coutHalf.
__global__ __launch_bounds__(256, 4) void k_conv1(const float* __restrict__ x,
                                                  const float* __restrict__ wsc,
                                                  float* __restrict__ h) {
  __shared__ __align__(16) float wl[1600];
  __shared__ float bl[8];
  const int gch = blockIdx.z & 1;
  const int b = blockIdx.z >> 1;
  for (int i = threadIdx.x * 4; i < 1600; i += 1024) {
    int r = i >> 3;   // (ci*25+p)
    int c = i & 7;
    *(float4*)(wl + i) = *(const float4*)(wsc + OFF_WP + r * 16 + gch * 8 + c);
  }
  if (threadIdx.x < 8) bl[threadIdx.x] = wsc[OFF_B1 + gch * 8 + threadIdx.x];
  __syncthreads();

  const int c0 = (blockIdx.x * 256 + threadIdx.x) * 4;
  const int y = blockIdx.y;
  const bool interior = (c0 >= 4) && (c0 + 8 <= TW);

  float acc[8][4];
#pragma unroll
  for (int co = 0; co < 8; co++)
#pragma unroll
    for (int j = 0; j < 4; j++) acc[co][j] = 0.f;

  for (int ci = 0; ci < 8; ci++) {
    const float* xc = x + (size_t)(b * 8 + ci) * HH * TW;
#pragma unroll
    for (int kh = 0; kh < 5; kh++) {
      const int yy = y + kh - 2;
      float xr[12];
      if (yy >= 0 && yy < HH) {
        const float* row = xc + (size_t)yy * TW;
        if (interior) {
#pragma unroll
          for (int v = 0; v < 3; v++)
            *(float4*)(xr + 4 * v) = *(const float4*)(row + c0 - 4 + 4 * v);
        } else {
#pragma unroll
          for (int j = 0; j < 12; j++) {
            int cc = c0 - 4 + j;
            xr[j] = (cc >= 0 && cc < TW) ? row[cc] : 0.f;
          }
        }
      } else {
#pragma unroll
        for (int j = 0; j < 12; j++) xr[j] = 0.f;
      }
      const float* wp = wl + (ci * 25 + kh * 5) * 8;
#pragma unroll
      for (int kw = 0; kw < 5; kw++) {
        const float4 wa = *(const float4*)(wp + kw * 8);
        const float4 wb = *(const float4*)(wp + kw * 8 + 4);
#pragma unroll
        for (int j = 0; j < 4; j++) {
          const float xv = xr[2 + kw + j];
          acc[0][j] = fmaf(xv, wa.x, acc[0][j]);
          acc[1][j] = fmaf(xv, wa.y, acc[1][j]);
          acc[2][j] = fmaf(xv, wa.z, acc[2][j]);
          acc[3][j] = fmaf(xv, wa.w, acc[3][j]);
          acc[4][j] = fmaf(xv, wb.x, acc[4][j]);
          acc[5][j] = fmaf(xv, wb.y, acc[5][j]);
          acc[6][j] = fmaf(xv, wb.z, acc[6][j]);
          acc[7][j] = fmaf(xv, wb.w, acc[7][j]);
        }
      }
    }
  }
  const size_t base = ((size_t)(b * 16 + gch * 8) * HH + y) * TW + c0;
#pragma unroll
  for (int co = 0; co < 8; co++) {
    float4 o;
    float z;
    z = acc[co][0] + bl[co]; o.x = (z >= 0.f) ? z : 0.01f * z;
    z = acc[co][1] + bl[co]; o.y = (z >= 0.f) ? z : 0.01f * z;
    z = acc[co][2] + bl[co]; o.z = (z >= 0.f) ? z : 0.01f * z;
    z = acc[co][3] + bl[co]; o.w = (z >= 0.f) ? z : 0.01f * z;
    *(float4*)(h + base + (size_t)co * HH * TW) = o;
  }
}

// ---------------- mask_sum per batch -----------------------------------------
__global__ void k_masksum(const float* __restrict__ frame, double* __restrict__ dacc) {
  const int b = blockIdx.y;
  const float* fr = frame + (size_t)b * FF * TW;
  double s = 0.0;
  for (int i = blockIdx.x * 256 + threadIdx.x; i < FF * TW; i += gridDim.x * 256)
    s += (double)fr[i];
  s = wsumd(s);
  __shared__ double sm[4];
  int lane = threadIdx.x & 63, wid = threadIdx.x >> 6;
  if (lane == 0) sm[wid] = s;
  __syncthreads();
  if (threadIdx.x == 0) atomAddD(&dacc[DO_MSUM + b], sm[0] + sm[1] + sm[2] + sm[3]);
}

// ---------------- conv2 Q-path: conv + proj + sigmoid + qsum -----------------
__global__ __launch_bounds__(256, 3) void k_conv2q(
    const float* __restrict__ h, const float* __restrict__ wsc,
    double* __restrict__ dacc,
    const float* __restrict__ fwq, const float* __restrict__ fbq,
    const float* __restrict__ bqc,
    float* __restrict__ qo) {
  __shared__ __align__(16) float wql[1728];
  for (int i = threadIdx.x * 4; i < 1728; i += 1024)
    *(float4*)(wql + i) = *(const float4*)(wsc + OFF_WQT + i);
  __syncthreads();

  const int c0 = (blockIdx.x * 256 + threadIdx.x) * 4;
  const int f = blockIdx.y;
  const int b = blockIdx.z;
  const bool interior = (c0 >= 4) && (c0 + 8 <= TW);

  float aq[12][4];
#pragma unroll
  for (int d = 0; d < 12; d++) {
    const float bq = bqc[d];
#pragma unroll
    for (int j = 0; j < 4; j++) aq[d][j] = bq;
  }

  for (int c = 0; c < 16; c++) {
    const float* hc = h + ((size_t)(b * 16 + c) * HH + 3 * f) * TW;
#pragma unroll
    for (int kh = 0; kh < 3; kh++) {
      const float* row = hc + (size_t)kh * TW;
      float xr[12];
      if (interior) {
#pragma unroll
        for (int v = 0; v < 3; v++)
          *(float4*)(xr + 4 * v) = *(const float4*)(row + c0 - 4 + 4 * v);
      } else {
#pragma unroll
        for (int j = 0; j < 12; j++) {
          int cc = c0 - 4 + j;
          xr[j] = (cc >= 0 && cc < TW) ? row[cc] : 0.f;
        }
      }
      const float* wp = wql + (c * 9 + kh * 3) * 12;
#pragma unroll
      for (int kw = 0; kw < 3; kw++) {
        const float4 w0 = *(const float4*)(wp + kw * 12);
        const float4 w1 = *(const float4*)(wp + kw * 12 + 4);
        const float4 w2 = *(const float4*)(wp + kw * 12 + 8);
        const float wv[12] = {w0.x, w0.y, w0.z, w0.w, w1.x, w1.y, w1.z, w1.w,
                              w2.x, w2.y, w2.z, w2.w};
#pragma unroll
        for (int j = 0; j < 4; j++) {
          const float xv = xr[3 + kw + j];
#pragma unroll
          for (int d = 0; d < 12; d++) aq[d][j] = fmaf(xv, wv[d], aq[d][j]);
        }
      }
    }
  }

  // projection: s1 = aq^T @ fwq + fbq  (e-outer to keep one weight row live)
  float s1[12][4];
#pragma unroll
  for (int d = 0; d < 12; d++) {
    const float bb = fbq[d];
#pragma unroll
    for (int j = 0; j < 4; j++) s1[d][j] = bb;
  }
#pragma unroll
  for (int e = 0; e < 12; e++) {
    const float4 w0 = *(const float4*)(fwq + e * 12);
    const float4 w1 = *(const float4*)(fwq + e * 12 + 4);
    const float4 w2 = *(const float4*)(fwq + e * 12 + 8);
    const float wv[12] = {w0.x, w0.y, w0.z, w0.w, w1.x, w1.y, w1.z, w1.w,
                          w2.x, w2.y, w2.z, w2.w};
#pragma unroll
    for (int j = 0; j < 4; j++) {
      const float a = aq[e][j];
#pragma unroll
      for (int d = 0; d < 12; d++) s1[d][j] = fmaf(a, wv[d], s1[d][j]);
    }
  }

  float qsumP[12];
#pragma unroll
  for (int d = 0; d < 12; d++) qsumP[d] = 0.f;
  const size_t lbase = (size_t)f * TW + c0;
#pragma unroll
  for (int j = 0; j < 4; j++) {
    const size_t o = ((size_t)b * LLEN + lbase + j) * 12;
#pragma unroll
    for (int d = 0; d < 12; d++) {
      const float qv = sigm(s1[d][j]);
      qsumP[d] += qv;
      qo[o + d] = qv;
    }
  }

  __shared__ float red[4 * 12];
  int lane = threadIdx.x & 63, wid = threadIdx.x >> 6;
#pragma unroll
  for (int d = 0; d < 12; d++) {
    float s = wsum(qsumP[d]);
    if (lane == 0) red[wid * 12 + d] = s;
  }
  __syncthreads();
  if (threadIdx.x < 12) {
    float tot = red[threadIdx.x] + red[12 + threadIdx.x] + red[24 + threadIdx.x] + red[36 + threadIdx.x];
    atomAddD(&dacc[DO_QSUM + b * 12 + threadIdx.x], (double)tot);
  }
}

// ---------------- conv2 KV-path: conv + masknorm + projK/V + sigmoid + ksum --
__global__ __launch_bounds__(256, 3) void k_conv2kv(
    const float* __restrict__ h, const float* __restrict__ frame,
    const float* __restrict__ wsc, double* __restrict__ dacc,
    const float* __restrict__ fwk, const float* __restrict__ fbk,
    const float* __restrict__ fwv, const float* __restrict__ fbv,
    const float* __restrict__ bkvc, const float* __restrict__ Tp,
    float* __restrict__ ko, float* __restrict__ vo) {
  __shared__ __align__(16) float wkl[1728];
  for (int i = threadIdx.x * 4; i < 1728; i += 1024)
    *(float4*)(wkl + i) = *(const float4*)(wsc + OFF_WKT + i);
  __syncthreads();

  const int c0 = (blockIdx.x * 256 + threadIdx.x) * 4;
  const int f = blockIdx.y;
  const int b = blockIdx.z;
  const bool interior = (c0 >= 4) && (c0 + 8 <= TW);

  float akv[12][4];
#pragma unroll
  for (int d = 0; d < 12; d++) {
    const float bk = bkvc[d];
#pragma unroll
    for (int j = 0; j < 4; j++) akv[d][j] = bk;
  }

  for (int c = 0; c < 16; c++) {
    const float* hc = h + ((size_t)(b * 16 + c) * HH + 3 * f) * TW;
#pragma unroll
    for (int kh = 0; kh < 3; kh++) {
      const float* row = hc + (size_t)kh * TW;
      float xr[12];
      if (interior) {
#pragma unroll
        for (int v = 0; v < 3; v++)
          *(float4*)(xr + 4 * v) = *(const float4*)(row + c0 - 4 + 4 * v);
      } else {
#pragma unroll
        for (int j = 0; j < 12; j++) {
          int cc = c0 - 4 + j;
          xr[j] = (cc >= 0 && cc < TW) ? row[cc] : 0.f;
        }
      }
      const float* wp = wkl + (c * 9 + kh * 3) * 12;
#pragma unroll
      for (int kw = 0; kw < 3; kw++) {
        const float4 w0 = *(const float4*)(wp + kw * 12);
        const float4 w1 = *(const float4*)(wp + kw * 12 + 4);
        const float4 w2 = *(const float4*)(wp + kw * 12 + 8);
        const float wv[12] = {w0.x, w0.y, w0.z, w0.w, w1.x, w1.y, w1.z, w1.w,
                              w2.x, w2.y, w2.z, w2.w};
#pragma unroll
        for (int j = 0; j < 4; j++) {
          const float xv = xr[3 + kw + j];
#pragma unroll
          for (int d = 0; d < 12; d++) akv[d][j] = fmaf(xv, wv[d], akv[d][j]);
        }
      }
    }
  }

  // masknorm (mask_norm=True) * T : scale akv in place
  const float msum = (float)dacc[DO_MSUM + b];
  const float Tv = Tp[0];
  const float4 mk4 = *(const float4*)(frame + ((size_t)b * FF + f) * TW + c0);
  const float mks[4] = {mk4.x, mk4.y, mk4.z, mk4.w};
#pragma unroll
  for (int j = 0; j < 4; j++) {
    float ss = EPSF;
#pragma unroll
    for (int d = 0; d < 12; d++) ss = fmaf(akv[d][j], akv[d][j], ss);
    const float sc = mks[j] * Tv / (sqrtf(ss) * msum);
#pragma unroll
    for (int d = 0; d < 12; d++) akv[d][j] *= sc;
  }

  const size_t lbase = (size_t)f * TW + c0;
  float ksumP[12];
#pragma unroll
  for (int d = 0; d < 12; d++) ksumP[d] = 0.f;

  // K projection + sigmoid + store + ksum
  {
    float s2[12][4];
#pragma unroll
    for (int d = 0; d < 12; d++) {
      const float bb = fbk[d];
#pragma unroll
      for (int j = 0; j < 4; j++) s2[d][j] = bb;
    }
#pragma unroll
    for (int e = 0; e < 12; e++) {
      const float4 w0 = *(const float4*)(fwk + e * 12);
      const float4 w1 = *(const float4*)(fwk + e * 12 + 4);
      const float4 w2 = *(const float4*)(fwk + e * 12 + 8);
      const float wv[12] = {w0.x, w0.y, w0.z, w0.w, w1.x, w1.y, w1.z, w1.w,
                            w2.x, w2.y, w2.z, w2.w};
#pragma unroll
      for (int j = 0; j < 4; j++) {
        const float a = akv[e][j];
#pragma unroll
        for (int d = 0; d < 12; d++) s2[d][j] = fmaf(a, wv[d], s2[d][j]);
      }
    }
#pragma unroll
    for (int j = 0; j < 4; j++) {
      const size_t o = ((size_t)b * LLEN + lbase + j) * 12;
#pragma unroll
      for (int d = 0; d < 12; d++) {
        const float kk = sigm(s2[d][j]);
        ksumP[d] += kk;
        ko[o + d] = kk;
      }
    }
  }

  // V projection + store
  {
    float s3[12][4];
#pragma unroll
    for (int d = 0; d < 12; d++) {
      const float bb = fbv[d];
#pragma unroll
      for (int j = 0; j < 4; j++) s3[d][j] = bb;
    }
#pragma unroll
    for (int e = 0; e < 12; e++) {
      const float4 w0 = *(const float4*)(fwv + e * 12);
      const float4 w1 = *(const float4*)(fwv + e * 12 + 4);
      const float4 w2 = *(const float4*)(fwv + e * 12 + 8);
      const float wv[12] = {w0.x, w0.y, w0.z, w0.w, w1.x, w1.y, w1.z, w1.w,
                            w2.x, w2.y, w2.z, w2.w};
#pragma unroll
      for (int j = 0; j < 4; j++) {
        const float a = akv[e][j];
#pragma unroll
        for (int d = 0; d < 12; d++) s3[d][j] = fmaf(a, wv[d], s3[d][j]);
      }
    }
#pragma unroll
    for (int j = 0; j < 4; j++) {
      const size_t o = ((size_t)b * LLEN + lbase + j) * 12;
#pragma unroll
      for (int d = 0; d < 12; d++) vo[o + d] = s3[d][j];
    }
  }

  __shared__ float red[4 * 12];
  int lane = threadIdx.x & 63, wid = threadIdx.x >> 6;
#pragma unroll
  for (int d = 0; d < 12; d++) {
    float s = wsum(ksumP[d]);
    if (lane == 0) red[wid * 12 + d] = s;
  }
  __syncthreads();
  if (threadIdx.x < 12) {
    float tot = red[threadIdx.x] + red[12 + threadIdx.x] + red[24 + threadIdx.x] + red[36 + threadIdx.x];
    atomAddD(&dacc[DO_KSUM + b * 12 + threadIdx.x], (double)tot);
  }
}

// ---------------- sink_in / src_out + skq,sqs reductions ---------------------
__global__ __launch_bounds__(256) void k_sink(const float* __restrict__ q,
                                              const float* __restrict__ k,
                                              float* __restrict__ sink_in,
                                              double* __restrict__ dacc) {
  const int b = blockIdx.y;
  const int tid0 = blockIdx.x * 256 + threadIdx.x;  // [0, 21504)
  float ksE[12], qsE[12];
#pragma unroll
  for (int d = 0; d < 12; d++) {
    ksE[d] = (float)(dacc[DO_KSUM + b * 12 + d] + (double)EPSF);
    qsE[d] = (float)(dacc[DO_QSUM + b * 12 + d] + (double)EPSF);
  }
  float askq[12], asqs[12];
#pragma unroll
  for (int d = 0; d < 12; d++) { askq[d] = 0.f; asqs[d] = 0.f; }
  for (int it = 0; it < 8; it++) {
    size_t l = (size_t)it * 21504 + tid0;
    const float* qp = q + ((size_t)b * LLEN + l) * 12;
    const float* kp = k + ((size_t)b * LLEN + l) * 12;
    float qv[12], kv[12];
#pragma unroll
    for (int d = 0; d < 12; d++) { qv[d] = qp[d]; kv[d] = kp[d]; }
    float s1 = 0.f, s2 = 0.f;
#pragma unroll
    for (int d = 0; d < 12; d++) {
      s1 = fmaf(qv[d] + EPSF, ksE[d], s1);
      s2 = fmaf(kv[d] + EPSF, qsE[d], s2);
    }
    float si = 1.f / s1;
    float so = 1.f / s2;
    sink_in[(size_t)b * LLEN + l] = si;
#pragma unroll
    for (int d = 0; d < 12; d++) {
      askq[d] = fmaf(kv[d], so, askq[d]);
      asqs[d] = fmaf(qv[d], si, asqs[d]);
    }
  }
  float part[24];
#pragma unroll
  for (int d = 0; d < 12; d++) { part[d] = askq[d]; part[12 + d] = asqs[d]; }
  __shared__ float red[4 * 24];
  int lane = threadIdx.x & 63, wid = threadIdx.x >> 6;
#pragma unroll
  for (int j = 0; j < 24; j++) {
    float s = wsum(part[j]);
    if (lane == 0) red[wid * 24 + j] = s;
  }
  __syncthreads();
  if (threadIdx.x < 24) {
    float tot = red[threadIdx.x] + red[24 + threadIdx.x] + red[48 + threadIdx.x] + red[72 + threadIdx.x];
    int idx = (threadIdx.x < 12) ? (DO_SKQ + b * 12 + threadIdx.x)
                                 : (DO_SQS + b * 12 + (threadIdx.x - 12));
    atomAddD(&dacc[idx], (double)tot);
  }
}

// ---------------- sink_alloc + exp(cons_src) + kv-matrix + sumexp ------------
__global__ __launch_bounds__(256) void k_flow(const float* __restrict__ q,
                                              const float* __restrict__ k,
                                              const float* __restrict__ v,
                                              float* __restrict__ sink_alloc,
                                              double* __restrict__ dacc) {
  const int b = blockIdx.y;
  const int tid0 = blockIdx.x * 256 + threadIdx.x;  // [0, 43008)
  float skqE[12], sqsE[12];
#pragma unroll
  for (int d = 0; d < 12; d++) {
    skqE[d] = (float)(dacc[DO_SKQ + b * 12 + d] + (double)EPSF);
    sqsE[d] = (float)(dacc[DO_SQS + b * 12 + d] + (double)EPSF);
  }
  float acc[144];
#pragma unroll
  for (int j = 0; j < 144; j++) acc[j] = 0.f;
  double se = 0.0;
  for (int it = 0; it < 4; it++) {
    size_t l = (size_t)it * 43008 + tid0;
    size_t o = ((size_t)b * LLEN + l) * 12;
    float qv[12], kv[12], vv[12];
#pragma unroll
    for (int d = 0; d < 12; d++) { qv[d] = q[o + d]; kv[d] = k[o + d]; vv[d] = v[o + d]; }
    float c1 = 0.f, c2 = 0.f;
#pragma unroll
    for (int d = 0; d < 12; d++) {
      c1 = fmaf(qv[d] + EPSF, skqE[d], c1);
      c2 = fmaf(kv[d] + EPSF, sqsE[d], c2);
    }
    sink_alloc[(size_t)b * LLEN + l] = sigm(c1);
    float e = expf(c2);
    se += (double)e;
#pragma unroll
    for (int d = 0; d < 12; d++) {
      float ke = kv[d] * e;
#pragma unroll
      for (int m = 0; m < 12; m++) acc[d * 12 + m] = fmaf(ke, vv[m], acc[d * 12 + m]);
    }
  }
  __shared__ float red[4 * 144];
  __shared__ double seds[4];
  int lane = threadIdx.x & 63, wid = threadIdx.x >> 6;
#pragma unroll
  for (int j = 0; j < 144; j++) {
    float s = wsum(acc[j]);
    if (lane == 0) red[wid * 144 + j] = s;
  }
  double sew = wsumd(se);
  if (lane == 0) seds[wid] = sew;
  __syncthreads();
  if (threadIdx.x < 144) {
    float tot = red[threadIdx.x] + red[144 + threadIdx.x] + red[288 + threadIdx.x] + red[432 + threadIdx.x];
    atomAddD(&dacc[DO_M + b * 144 + threadIdx.x], (double)tot);
  }
  if (threadIdx.x == 192) atomAddD(&dacc[DO_SE + b], seds[0] + seds[1] + seds[2] + seds[3]);
}

// ---------------- final: out = (q@kv)*sink_in*sink_alloc @ Wo + bo -----------
__global__ __launch_bounds__(256) void k_out(const float* __restrict__ q,
                                             const float* __restrict__ sink_in,
                                             const float* __restrict__ sink_alloc,
                                             const double* __restrict__ dacc,
                                             const float* __restrict__ wo,
                                             const float* __restrict__ bo,
                                             float* __restrict__ out) {
  const int t = blockIdx.x * 256 + threadIdx.x;
  const int f = blockIdx.y;
  const int b = blockIdx.z;
  __shared__ float kvf[144];
  if (threadIdx.x < 144) {
    double fac = (double)LLEN / dacc[DO_SE + b];
    kvf[threadIdx.x] = (float)(dacc[DO_M + b * 144 + threadIdx.x] * fac);
  }
  __syncthreads();
  size_t l = (size_t)f * TW + t;
  const float* qp = q + ((size_t)b * LLEN + l) * 12;
  float qv[12];
#pragma unroll
  for (int d = 0; d < 12; d++) qv[d] = qp[d];
  float s = sink_in[(size_t)b * LLEN + l] * sink_alloc[(size_t)b * LLEN + l];
  float o[12];
#pragma unroll
  for (int m = 0; m < 12; m++) {
    float a = 0.f;
#pragma unroll
    for (int d = 0; d < 12; d++) a = fmaf(qv[d], kvf[d * 12 + m], a);
    o[m] = a * s;
  }
#pragma unroll
  for (int m2 = 0; m2 < 12; m2++) {
    float a = bo[m2];
#pragma unroll
    for (int m = 0; m < 12; m++) a = fmaf(o[m], wo[m * 12 + m2], a);
    out[((size_t)b * 12 + m2) * LLEN + l] = a;
  }
}

extern "C" void kernel_launch(void* const* d_in, const int* in_sizes, int n_in,
                              void* d_out, int out_size, void* d_ws, size_t ws_size,
                              hipStream_t stream) {
  (void)in_sizes; (void)n_in; (void)out_size; (void)ws_size;
  const float* x     = (const float*)d_in[0];
  const float* frame = (const float*)d_in[1];
  const float* w_pre = (const float*)d_in[2];
  const float* b_pre = (const float*)d_in[3];
  const float* gam   = (const float*)d_in[4];
  const float* bet   = (const float*)d_in[5];
  const float* mean  = (const float*)d_in[6];
  const float* var   = (const float*)d_in[7];
  const float* Tp    = (const float*)d_in[8];
  const float* wq_c  = (const float*)d_in[9];
  const float* bq_c  = (const float*)d_in[10];
  const float* wkv_c = (const float*)d_in[11];
  const float* bkv_c = (const float*)d_in[12];
  const float* fa_wq = (const float*)d_in[13];
  const float* fa_bq = (const float*)d_in[14];
  const float* fa_wk = (const float*)d_in[15];
  const float* fa_bk = (const float*)d_in[16];
  const float* fa_wv = (const float*)d_in[17];
  const float* fa_bv = (const float*)d_in[18];
  const float* fa_wo = (const float*)d_in[19];
  const float* fa_bo = (const float*)d_in[20];

  float* ws = (float*)d_ws;
  double* dacc = (double*)((char*)d_ws + DBYTE);
  float* out = (float*)d_out;

  hipMemsetAsync(dacc, 0, NDBL * sizeof(double), stream);
  k_prep<<<dim3(16), 256, 0, stream>>>(w_pre, b_pre, gam, bet, mean, var, wq_c, wkv_c, ws);
  k_masksum<<<dim3(64, 4), 256, 0, stream>>>(frame, dacc);
  k_conv1<<<dim3(2, 252, 8), 256, 0, stream>>>(x, ws, ws + OFF_H);
  k_conv2q<<<dim3(2, 84, 4), 256, 0, stream>>>(ws + OFF_H, ws, dacc,
      fa_wq, fa_bq, bq_c, ws + OFF_Q);
  k_conv2kv<<<dim3(2, 84, 4), 256, 0, stream>>>(ws + OFF_H, frame, ws, dacc,
      fa_wk, fa_bk, fa_wv, fa_bv, bkv_c, Tp, ws + OFF_K, ws + OFF_V);
  k_sink<<<dim3(84, 4), 256, 0, stream>>>(ws + OFF_Q, ws + OFF_K, ws + OFF_SI, dacc);
  k_flow<<<dim3(168, 4), 256, 0, stream>>>(ws + OFF_Q, ws + OFF_K, ws + OFF_V, ws + OFF_SA, dacc);
  k_out<<<dim3(8, 84, 4), 256, 0, stream>>>(ws + OFF_Q, ws + OFF_SI, ws + OFF_SA, dacc,
      fa_wo, fa_bo, out);
}

// Round 7
// 615.615 us; speedup vs baseline: 3.0267x; 3.0267x over previous
//
#include <hip/hip_runtime.h>
#include <math.h>

#define EPSF 1.01e-08f

namespace {
constexpr int NB = 4;                 // batch
constexpr int HH = 252, TW = 2048;    // conv1 spatial
constexpr int C1 = 16, DD = 12, FF = 84;
constexpr int LLEN = FF * TW;         // 172032

// workspace layout (float elements)
constexpr size_t OFF_H   = 0;
constexpr size_t SZ_H    = (size_t)NB * C1 * HH * TW;       // 33,030,144
constexpr size_t SZ_QKV  = (size_t)NB * LLEN * DD;          // 8,257,536
constexpr size_t OFF_Q   = OFF_H + SZ_H;
constexpr size_t OFF_K   = OFF_Q + SZ_QKV;
constexpr size_t OFF_V   = OFF_K + SZ_QKV;
constexpr size_t OFF_SI  = OFF_V + SZ_QKV;                  // sink_in  (NB*LLEN)
constexpr size_t OFF_SA  = OFF_SI + (size_t)NB * LLEN;      // sink_alloc
constexpr size_t OFF_WP  = OFF_SA + (size_t)NB * LLEN;      // folded conv1 w (3200)
constexpr size_t OFF_B1  = OFF_WP + 3200;                   // folded conv1 b (16)
constexpr size_t OFF_WQT = OFF_B1 + 16;                     // wq transposed (1728)
constexpr size_t OFF_WKT = OFF_WQT + 1728;                  // wkv transposed (1728)
constexpr size_t FTOT    = OFF_WKT + 1728;
constexpr size_t DBYTE   = FTOT * sizeof(float);            // 8-byte aligned

// f64 accumulator slots (index into double*)
constexpr int DO_MSUM = 0;     // 4
constexpr int DO_KSUM = 4;     // 4*12
constexpr int DO_QSUM = 52;    // 4*12
constexpr int DO_SKQ  = 100;   // 4*12
constexpr int DO_SQS  = 148;   // 4*12
constexpr int DO_SE   = 196;   // 4
constexpr int DO_M    = 200;   // 4*144
constexpr int NDBL    = 776;
}

__device__ __forceinline__ float wsum(float v) {
#pragma unroll
  for (int m = 1; m < 64; m <<= 1) v += __shfl_xor(v, m, 64);
  return v;
}
__device__ __forceinline__ double wsumd(double v) {
#pragma unroll
  for (int m = 1; m < 64; m <<= 1) v += __shfl_xor(v, m, 64);
  return v;
}
__device__ __forceinline__ void atomAddD(double* p, double v) { unsafeAtomicAdd(p, v); }
__device__ __forceinline__ float sigm(float x) { return 1.f / (1.f + expf(-x)); }

// ---------------- weight prep: fold BN into conv1, transpose conv2 weights ----
__global__ void k_prep(const float* __restrict__ w_pre, const float* __restrict__ b_pre,
                       const float* __restrict__ g, const float* __restrict__ be,
                       const float* __restrict__ mean, const float* __restrict__ var,
                       const float* __restrict__ wq, const float* __restrict__ wkv,
                       float* __restrict__ ws) {
  int tid = blockIdx.x * 256 + threadIdx.x;
  int stride = gridDim.x * 256;
  if (tid < 16) {
    float sc = g[tid] / sqrtf(var[tid] + 1e-5f);
    ws[OFF_B1 + tid] = (b_pre[tid] - mean[tid]) * sc + be[tid];
  }
  for (int idx = tid; idx < 3200; idx += stride) {
    int co = idx & 15, r = idx >> 4;     // r = ci*25 + p
    int ci = r / 25, p = r % 25;
    float sc = g[co] / sqrtf(var[co] + 1e-5f);
    ws[OFF_WP + idx] = w_pre[(co * 8 + ci) * 25 + p] * sc;
  }
  for (int idx = tid; idx < 1728; idx += stride) {
    int d = idx % 12, r = idx / 12;      // r = c*9 + p
    ws[OFF_WQT + idx] = wq[d * 144 + r];
    ws[OFF_WKT + idx] = wkv[d * 144 + r];
  }
}

// ---------------- conv1 5x5 same + BN(folded) + LeakyReLU --------------------
// Block tile: 512 cols x 2 out rows x 16 couts, one batch. x staged in LDS
// per-ci (6 rows x 520 cols). Thread: 2 cols x 2 rows x 16 couts = 64 acc.
__global__ __launch_bounds__(256, 3) void k_conv1(const float* __restrict__ x,
                                                  const float* __restrict__ wsc,
                                                  float* __restrict__ h) {
  __shared__ __align__(16) float wl[3200];
  __shared__ float bl[16];
  __shared__ __align__(16) float xs[6][520];

  const int cb = blockIdx.x * 512;
  const int y0 = blockIdx.y * 2;
  const int b = blockIdx.z;

  for (int i = threadIdx.x * 4; i < 3200; i += 1024)
    *(float4*)(wl + i) = *(const float4*)(wsc + OFF_WP + i);
  if (threadIdx.x < 16) bl[threadIdx.x] = wsc[OFF_B1 + threadIdx.x];

  float acc[16][2][2];
#pragma unroll
  for (int co = 0; co < 16; co++)
#pragma unroll
    for (int r = 0; r < 2; r++)
#pragma unroll
      for (int c = 0; c < 2; c++) acc[co][r][c] = 0.f;

  const int lc = (int)threadIdx.x * 2;   // local col [0,512)

  for (int ci = 0; ci < 8; ci++) {
    __syncthreads();   // previous iter readers done (and ci=0: weights staged)
    const float* xc = x + (size_t)(b * 8 + ci) * HH * TW;
    for (int li = threadIdx.x; li < 6 * 520; li += 256) {
      const int r = li / 520;
      const int c = li - r * 520;
      const int gy = y0 - 2 + r;
      const int gx = cb - 2 + c;
      float v = 0.f;
      if (gy >= 0 && gy < HH && gx >= 0 && gx < TW) v = xc[(size_t)gy * TW + gx];
      xs[r][c] = v;
    }
    __syncthreads();

#pragma unroll
    for (int kh = 0; kh < 5; kh++) {
      float ra[6], rb[6];
#pragma unroll
      for (int u = 0; u < 3; u++) {
        const float2 a = *(const float2*)(&xs[kh][lc + 2 * u]);
        const float2 bv = *(const float2*)(&xs[kh + 1][lc + 2 * u]);
        ra[2 * u] = a.x; ra[2 * u + 1] = a.y;
        rb[2 * u] = bv.x; rb[2 * u + 1] = bv.y;
      }
      const float* wrow = wl + (ci * 25 + kh * 5) * 16;
#pragma unroll
      for (int kw = 0; kw < 5; kw++) {
        const float4 wA = *(const float4*)(wrow + kw * 16);
        const float4 wB = *(const float4*)(wrow + kw * 16 + 4);
        const float4 wC = *(const float4*)(wrow + kw * 16 + 8);
        const float4 wD = *(const float4*)(wrow + kw * 16 + 12);
        const float wv[16] = {wA.x, wA.y, wA.z, wA.w, wB.x, wB.y, wB.z, wB.w,
                              wC.x, wC.y, wC.z, wC.w, wD.x, wD.y, wD.z, wD.w};
        const float x00 = ra[kw], x01 = ra[kw + 1];
        const float x10 = rb[kw], x11 = rb[kw + 1];
#pragma unroll
        for (int co = 0; co < 16; co++) {
          acc[co][0][0] = fmaf(x00, wv[co], acc[co][0][0]);
          acc[co][0][1] = fmaf(x01, wv[co], acc[co][0][1]);
          acc[co][1][0] = fmaf(x10, wv[co], acc[co][1][0]);
          acc[co][1][1] = fmaf(x11, wv[co], acc[co][1][1]);
        }
      }
    }
  }

#pragma unroll
  for (int co = 0; co < 16; co++) {
    const float bb = bl[co];
#pragma unroll
    for (int r = 0; r < 2; r++) {
      float2 o;
      const float z0 = acc[co][r][0] + bb; o.x = (z0 >= 0.f) ? z0 : 0.01f * z0;
      const float z1 = acc[co][r][1] + bb; o.y = (z1 >= 0.f) ? z1 : 0.01f * z1;
      *(float2*)(h + ((size_t)(b * 16 + co) * HH + (y0 + r)) * TW + cb + lc) = o;
    }
  }
}

// ---------------- mask_sum per batch -----------------------------------------
__global__ void k_masksum(const float* __restrict__ frame, double* __restrict__ dacc) {
  const int b = blockIdx.y;
  const float* fr = frame + (size_t)b * FF * TW;
  double s = 0.0;
  for (int i = blockIdx.x * 256 + threadIdx.x; i < FF * TW; i += gridDim.x * 256)
    s += (double)fr[i];
  s = wsumd(s);
  __shared__ double sm[4];
  int lane = threadIdx.x & 63, wid = threadIdx.x >> 6;
  if (lane == 0) sm[wid] = s;
  __syncthreads();
  if (threadIdx.x == 0) atomAddD(&dacc[DO_MSUM + b], sm[0] + sm[1] + sm[2] + sm[3]);
}

// ---------------- conv2 Q-path: conv + proj + sigmoid + qsum -----------------
__global__ __launch_bounds__(256, 3) void k_conv2q(
    const float* __restrict__ h, const float* __restrict__ wsc,
    double* __restrict__ dacc,
    const float* __restrict__ fwq, const float* __restrict__ fbq,
    const float* __restrict__ bqc,
    float* __restrict__ qo) {
  __shared__ __align__(16) float wql[1728];
  for (int i = threadIdx.x * 4; i < 1728; i += 1024)
    *(float4*)(wql + i) = *(const float4*)(wsc + OFF_WQT + i);
  __syncthreads();

  const int c0 = (blockIdx.x * 256 + threadIdx.x) * 4;
  const int f = blockIdx.y;
  const int b = blockIdx.z;
  const bool interior = (c0 >= 4) && (c0 + 8 <= TW);

  float aq[12][4];
#pragma unroll
  for (int d = 0; d < 12; d++) {
    const float bq = bqc[d];
#pragma unroll
    for (int j = 0; j < 4; j++) aq[d][j] = bq;
  }

  for (int c = 0; c < 16; c++) {
    const float* hc = h + ((size_t)(b * 16 + c) * HH + 3 * f) * TW;
#pragma unroll
    for (int kh = 0; kh < 3; kh++) {
      const float* row = hc + (size_t)kh * TW;
      float xr[12];
      if (interior) {
#pragma unroll
        for (int v = 0; v < 3; v++)
          *(float4*)(xr + 4 * v) = *(const float4*)(row + c0 - 4 + 4 * v);
      } else {
#pragma unroll
        for (int j = 0; j < 12; j++) {
          int cc = c0 - 4 + j;
          xr[j] = (cc >= 0 && cc < TW) ? row[cc] : 0.f;
        }
      }
      const float* wp = wql + (c * 9 + kh * 3) * 12;
#pragma unroll
      for (int kw = 0; kw < 3; kw++) {
        const float4 w0 = *(const float4*)(wp + kw * 12);
        const float4 w1 = *(const float4*)(wp + kw * 12 + 4);
        const float4 w2 = *(const float4*)(wp + kw * 12 + 8);
        const float wv[12] = {w0.x, w0.y, w0.z, w0.w, w1.x, w1.y, w1.z, w1.w,
                              w2.x, w2.y, w2.z, w2.w};
#pragma unroll
        for (int j = 0; j < 4; j++) {
          const float xv = xr[3 + kw + j];
#pragma unroll
          for (int d = 0; d < 12; d++) aq[d][j] = fmaf(xv, wv[d], aq[d][j]);
        }
      }
    }
  }

  // projection: s1 = aq^T @ fwq + fbq  (e-outer to keep one weight row live)
  float s1[12][4];
#pragma unroll
  for (int d = 0; d < 12; d++) {
    const float bb = fbq[d];
#pragma unroll
    for (int j = 0; j < 4; j++) s1[d][j] = bb;
  }
#pragma unroll
  for (int e = 0; e < 12; e++) {
    const float4 w0 = *(const float4*)(fwq + e * 12);
    const float4 w1 = *(const float4*)(fwq + e * 12 + 4);
    const float4 w2 = *(const float4*)(fwq + e * 12 + 8);
    const float wv[12] = {w0.x, w0.y, w0.z, w0.w, w1.x, w1.y, w1.z, w1.w,
                          w2.x, w2.y, w2.z, w2.w};
#pragma unroll
    for (int j = 0; j < 4; j++) {
      const float a = aq[e][j];
#pragma unroll
      for (int d = 0; d < 12; d++) s1[d][j] = fmaf(a, wv[d], s1[d][j]);
    }
  }

  float qsumP[12];
#pragma unroll
  for (int d = 0; d < 12; d++) qsumP[d] = 0.f;
  const size_t lbase = (size_t)f * TW + c0;
#pragma unroll
  for (int j = 0; j < 4; j++) {
    const size_t o = ((size_t)b * LLEN + lbase + j) * 12;
#pragma unroll
    for (int d = 0; d < 12; d++) {
      const float qv = sigm(s1[d][j]);
      qsumP[d] += qv;
      qo[o + d] = qv;
    }
  }

  __shared__ float red[4 * 12];
  int lane = threadIdx.x & 63, wid = threadIdx.x >> 6;
#pragma unroll
  for (int d = 0; d < 12; d++) {
    float s = wsum(qsumP[d]);
    if (lane == 0) red[wid * 12 + d] = s;
  }
  __syncthreads();
  if (threadIdx.x < 12) {
    float tot = red[threadIdx.x] + red[12 + threadIdx.x] + red[24 + threadIdx.x] + red[36 + threadIdx.x];
    atomAddD(&dacc[DO_QSUM + b * 12 + threadIdx.x], (double)tot);
  }
}

// ---------------- conv2 KV-path: conv + masknorm + projK/V + sigmoid + ksum --
__global__ __launch_bounds__(256, 3) void k_conv2kv(
    const float* __restrict__ h, const float* __restrict__ frame,
    const float* __restrict__ wsc, double* __restrict__ dacc,
    const float* __restrict__ fwk, const float* __restrict__ fbk,
    const float* __restrict__ fwv, const float* __restrict__ fbv,
    const float* __restrict__ bkvc, const float* __restrict__ Tp,
    float* __restrict__ ko, float* __restrict__ vo) {
  __shared__ __align__(16) float wkl[1728];
  for (int i = threadIdx.x * 4; i < 1728; i += 1024)
    *(float4*)(wkl + i) = *(const float4*)(wsc + OFF_WKT + i);
  __syncthreads();

  const int c0 = (blockIdx.x * 256 + threadIdx.x) * 4;
  const int f = blockIdx.y;
  const int b = blockIdx.z;
  const bool interior = (c0 >= 4) && (c0 + 8 <= TW);

  float akv[12][4];
#pragma unroll
  for (int d = 0; d < 12; d++) {
    const float bk = bkvc[d];
#pragma unroll
    for (int j = 0; j < 4; j++) akv[d][j] = bk;
  }

  for (int c = 0; c < 16; c++) {
    const float* hc = h + ((size_t)(b * 16 + c) * HH + 3 * f) * TW;
#pragma unroll
    for (int kh = 0; kh < 3; kh++) {
      const float* row = hc + (size_t)kh * TW;
      float xr[12];
      if (interior) {
#pragma unroll
        for (int v = 0; v < 3; v++)
          *(float4*)(xr + 4 * v) = *(const float4*)(row + c0 - 4 + 4 * v);
      } else {
#pragma unroll
        for (int j = 0; j < 12; j++) {
          int cc = c0 - 4 + j;
          xr[j] = (cc >= 0 && cc < TW) ? row[cc] : 0.f;
        }
      }
      const float* wp = wkl + (c * 9 + kh * 3) * 12;
#pragma unroll
      for (int kw = 0; kw < 3; kw++) {
        const float4 w0 = *(const float4*)(wp + kw * 12);
        const float4 w1 = *(const float4*)(wp + kw * 12 + 4);
        const float4 w2 = *(const float4*)(wp + kw * 12 + 8);
        const float wv[12] = {w0.x, w0.y, w0.z, w0.w, w1.x, w1.y, w1.z, w1.w,
                              w2.x, w2.y, w2.z, w2.w};
#pragma unroll
        for (int j = 0; j < 4; j++) {
          const float xv = xr[3 + kw + j];
#pragma unroll
          for (int d = 0; d < 12; d++) akv[d][j] = fmaf(xv, wv[d], akv[d][j]);
        }
      }
    }
  }

  // masknorm (mask_norm=True) * T : scale akv in place
  const float msum = (float)dacc[DO_MSUM + b];
  const float Tv = Tp[0];
  const float4 mk4 = *(const float4*)(frame + ((size_t)b * FF + f) * TW + c0);
  const float mks[4] = {mk4.x, mk4.y, mk4.z, mk4.w};
#pragma unroll
  for (int j = 0; j < 4; j++) {
    float ss = EPSF;
#pragma unroll
    for (int d = 0; d < 12; d++) ss = fmaf(akv[d][j], akv[d][j], ss);
    const float sc = mks[j] * Tv / (sqrtf(ss) * msum);
#pragma unroll
    for (int d = 0; d < 12; d++) akv[d][j] *= sc;
  }

  const size_t lbase = (size_t)f * TW + c0;
  float ksumP[12];
#pragma unroll
  for (int d = 0; d < 12; d++) ksumP[d] = 0.f;

  // K projection + sigmoid + store + ksum
  {
    float s2[12][4];
#pragma unroll
    for (int d = 0; d < 12; d++) {
      const float bb = fbk[d];
#pragma unroll
      for (int j = 0; j < 4; j++) s2[d][j] = bb;
    }
#pragma unroll
    for (int e = 0; e < 12; e++) {
      const float4 w0 = *(const float4*)(fwk + e * 12);
      const float4 w1 = *(const float4*)(fwk + e * 12 + 4);
      const float4 w2 = *(const float4*)(fwk + e * 12 + 8);
      const float wv[12] = {w0.x, w0.y, w0.z, w0.w, w1.x, w1.y, w1.z, w1.w,
                            w2.x, w2.y, w2.z, w2.w};
#pragma unroll
      for (int j = 0; j < 4; j++) {
        const float a = akv[e][j];
#pragma unroll
        for (int d = 0; d < 12; d++) s2[d][j] = fmaf(a, wv[d], s2[d][j]);
      }
    }
#pragma unroll
    for (int j = 0; j < 4; j++) {
      const size_t o = ((size_t)b * LLEN + lbase + j) * 12;
#pragma unroll
      for (int d = 0; d < 12; d++) {
        const float kk = sigm(s2[d][j]);
        ksumP[d] += kk;
        ko[o + d] = kk;
      }
    }
  }

  // V projection + store
  {
    float s3[12][4];
#pragma unroll
    for (int d = 0; d < 12; d++) {
      const float bb = fbv[d];
#pragma unroll
      for (int j = 0; j < 4; j++) s3[d][j] = bb;
    }
#pragma unroll
    for (int e = 0; e < 12; e++) {
      const float4 w0 = *(const float4*)(fwv + e * 12);
      const float4 w1 = *(const float4*)(fwv + e * 12 + 4);
      const float4 w2 = *(const float4*)(fwv + e * 12 + 8);
      const float wv[12] = {w0.x, w0.y, w0.z, w0.w, w1.x, w1.y, w1.z, w1.w,
                            w2.x, w2.y, w2.z, w2.w};
#pragma unroll
      for (int j = 0; j < 4; j++) {
        const float a = akv[e][j];
#pragma unroll
        for (int d = 0; d < 12; d++) s3[d][j] = fmaf(a, wv[d], s3[d][j]);
      }
    }
#pragma unroll
    for (int j = 0; j < 4; j++) {
      const size_t o = ((size_t)b * LLEN + lbase + j) * 12;
#pragma unroll
      for (int d = 0; d < 12; d++) vo[o + d] = s3[d][j];
    }
  }

  __shared__ float red[4 * 12];
  int lane = threadIdx.x & 63, wid = threadIdx.x >> 6;
#pragma unroll
  for (int d = 0; d < 12; d++) {
    float s = wsum(ksumP[d]);
    if (lane == 0) red[wid * 12 + d] = s;
  }
  __syncthreads();
  if (threadIdx.x < 12) {
    float tot = red[threadIdx.x] + red[12 + threadIdx.x] + red[24 + threadIdx.x] + red[36 + threadIdx.x];
    atomAddD(&dacc[DO_KSUM + b * 12 + threadIdx.x], (double)tot);
  }
}

// ---------------- sink_in / src_out + skq,sqs reductions ---------------------
__global__ __launch_bounds__(256) void k_sink(const float* __restrict__ q,
                                              const float* __restrict__ k,
                                              float* __restrict__ sink_in,
                                              double* __restrict__ dacc) {
  const int b = blockIdx.y;
  const int tid0 = blockIdx.x * 256 + threadIdx.x;  // [0, 21504)
  float ksE[12], qsE[12];
#pragma unroll
  for (int d = 0; d < 12; d++) {
    ksE[d] = (float)(dacc[DO_KSUM + b * 12 + d] + (double)EPSF);
    qsE[d] = (float)(dacc[DO_QSUM + b * 12 + d] + (double)EPSF);
  }
  float askq[12], asqs[12];
#pragma unroll
  for (int d = 0; d < 12; d++) { askq[d] = 0.f; asqs[d] = 0.f; }
  for (int it = 0; it < 8; it++) {
    size_t l = (size_t)it * 21504 + tid0;
    const float* qp = q + ((size_t)b * LLEN + l) * 12;
    const float* kp = k + ((size_t)b * LLEN + l) * 12;
    float qv[12], kv[12];
#pragma unroll
    for (int d = 0; d < 12; d++) { qv[d] = qp[d]; kv[d] = kp[d]; }
    float s1 = 0.f, s2 = 0.f;
#pragma unroll
    for (int d = 0; d < 12; d++) {
      s1 = fmaf(qv[d] + EPSF, ksE[d], s1);
      s2 = fmaf(kv[d] + EPSF, qsE[d], s2);
    }
    float si = 1.f / s1;
    float so = 1.f / s2;
    sink_in[(size_t)b * LLEN + l] = si;
#pragma unroll
    for (int d = 0; d < 12; d++) {
      askq[d] = fmaf(kv[d], so, askq[d]);
      asqs[d] = fmaf(qv[d], si, asqs[d]);
    }
  }
  float part[24];
#pragma unroll
  for (int d = 0; d < 12; d++) { part[d] = askq[d]; part[12 + d] = asqs[d]; }
  __shared__ float red[4 * 24];
  int lane = threadIdx.x & 63, wid = threadIdx.x >> 6;
#pragma unroll
  for (int j = 0; j < 24; j++) {
    float s = wsum(part[j]);
    if (lane == 0) red[wid * 24 + j] = s;
  }
  __syncthreads();
  if (threadIdx.x < 24) {
    float tot = red[threadIdx.x] + red[24 + threadIdx.x] + red[48 + threadIdx.x] + red[72 + threadIdx.x];
    int idx = (threadIdx.x < 12) ? (DO_SKQ + b * 12 + threadIdx.x)
                                 : (DO_SQS + b * 12 + (threadIdx.x - 12));
    atomAddD(&dacc[idx], (double)tot);
  }
}

// ---------------- sink_alloc + exp(cons_src) + kv-matrix + sumexp ------------
__global__ __launch_bounds__(256) void k_flow(const float* __restrict__ q,
                                              const float* __restrict__ k,
                                              const float* __restrict__ v,
                                              float* __restrict__ sink_alloc,
                                              double* __restrict__ dacc) {
  const int b = blockIdx.y;
  const int tid0 = blockIdx.x * 256 + threadIdx.x;  // [0, 43008)
  float skqE[12], sqsE[12];
#pragma unroll
  for (int d = 0; d < 12; d++) {
    skqE[d] = (float)(dacc[DO_SKQ + b * 12 + d] + (double)EPSF);
    sqsE[d] = (float)(dacc[DO_SQS + b * 12 + d] + (double)EPSF);
  }
  float acc[144];
#pragma unroll
  for (int j = 0; j < 144; j++) acc[j] = 0.f;
  double se = 0.0;
  for (int it = 0; it < 4; it++) {
    size_t l = (size_t)it * 43008 + tid0;
    size_t o = ((size_t)b * LLEN + l) * 12;
    float qv[12], kv[12], vv[12];
#pragma unroll
    for (int d = 0; d < 12; d++) { qv[d] = q[o + d]; kv[d] = k[o + d]; vv[d] = v[o + d]; }
    float c1 = 0.f, c2 = 0.f;
#pragma unroll
    for (int d = 0; d < 12; d++) {
      c1 = fmaf(qv[d] + EPSF, skqE[d], c1);
      c2 = fmaf(kv[d] + EPSF, sqsE[d], c2);
    }
    sink_alloc[(size_t)b * LLEN + l] = sigm(c1);
    float e = expf(c2);
    se += (double)e;
#pragma unroll
    for (int d = 0; d < 12; d++) {
      float ke = kv[d] * e;
#pragma unroll
      for (int m = 0; m < 12; m++) acc[d * 12 + m] = fmaf(ke, vv[m], acc[d * 12 + m]);
    }
  }
  __shared__ float red[4 * 144];
  __shared__ double seds[4];
  int lane = threadIdx.x & 63, wid = threadIdx.x >> 6;
#pragma unroll
  for (int j = 0; j < 144; j++) {
    float s = wsum(acc[j]);
    if (lane == 0) red[wid * 144 + j] = s;
  }
  double sew = wsumd(se);
  if (lane == 0) seds[wid] = sew;
  __syncthreads();
  if (threadIdx.x < 144) {
    float tot = red[threadIdx.x] + red[144 + threadIdx.x] + red[288 + threadIdx.x] + red[432 + threadIdx.x];
    atomAddD(&dacc[DO_M + b * 144 + threadIdx.x], (double)tot);
  }
  if (threadIdx.x == 192) atomAddD(&dacc[DO_SE + b], seds[0] + seds[1] + seds[2] + seds[3]);
}

// ---------------- final: out = (q@kv)*sink_in*sink_alloc @ Wo + bo -----------
__global__ __launch_bounds__(256) void k_out(const float* __restrict__ q,
                                             const float* __restrict__ sink_in,
                                             const float* __restrict__ sink_alloc,
                                             const double* __restrict__ dacc,
                                             const float* __restrict__ wo,
                                             const float* __restrict__ bo,
                                             float* __restrict__ out) {
  const int t = blockIdx.x * 256 + threadIdx.x;
  const int f = blockIdx.y;
  const int b = blockIdx.z;
  __shared__ float kvf[144];
  if (threadIdx.x < 144) {
    double fac = (double)LLEN / dacc[DO_SE + b];
    kvf[threadIdx.x] = (float)(dacc[DO_M + b * 144 + threadIdx.x] * fac);
  }
  __syncthreads();
  size_t l = (size_t)f * TW + t;
  const float* qp = q + ((size_t)b * LLEN + l) * 12;
  float qv[12];
#pragma unroll
  for (int d = 0; d < 12; d++) qv[d] = qp[d];
  float s = sink_in[(size_t)b * LLEN + l] * sink_alloc[(size_t)b * LLEN + l];
  float o[12];
#pragma unroll
  for (int m = 0; m < 12; m++) {
    float a = 0.f;
#pragma unroll
    for (int d = 0; d < 12; d++) a = fmaf(qv[d], kvf[d * 12 + m], a);
    o[m] = a * s;
  }
#pragma unroll
  for (int m2 = 0; m2 < 12; m2++) {
    float a = bo[m2];
#pragma unroll
    for (int m = 0; m < 12; m++) a = fmaf(o[m], wo[m * 12 + m2], a);
    out[((size_t)b * 12 + m2) * LLEN + l] = a;
  }
}

extern "C" void kernel_launch(void* const* d_in, const int* in_sizes, int n_in,
                              void* d_out, int out_size, void* d_ws, size_t ws_size,
                              hipStream_t stream) {
  (void)in_sizes; (void)n_in; (void)out_size; (void)ws_size;
  const float* x     = (const float*)d_in[0];
  const float* frame = (const float*)d_in[1];
  const float* w_pre = (const float*)d_in[2];
  const float* b_pre = (const float*)d_in[3];
  const float* gam   = (const float*)d_in[4];
  const float* bet   = (const float*)d_in[5];
  const float* mean  = (const float*)d_in[6];
  const float* var   = (const float*)d_in[7];
  const float* Tp    = (const float*)d_in[8];
  const float* wq_c  = (const float*)d_in[9];
  const float* bq_c  = (const float*)d_in[10];
  const float* wkv_c = (const float*)d_in[11];
  const float* bkv_c = (const float*)d_in[12];
  const float* fa_wq = (const float*)d_in[13];
  const float* fa_bq = (const float*)d_in[14];
  const float* fa_wk = (const float*)d_in[15];
  const float* fa_bk = (const float*)d_in[16];
  const float* fa_wv = (const float*)d_in[17];
  const float* fa_bv = (const float*)d_in[18];
  const float* fa_wo = (const float*)d_in[19];
  const float* fa_bo = (const float*)d_in[20];

  float* ws = (float*)d_ws;
  double* dacc = (double*)((char*)d_ws + DBYTE);
  float* out = (float*)d_out;

  hipMemsetAsync(dacc, 0, NDBL * sizeof(double), stream);
  k_prep<<<dim3(16), 256, 0, stream>>>(w_pre, b_pre, gam, bet, mean, var, wq_c, wkv_c, ws);
  k_masksum<<<dim3(64, 4), 256, 0, stream>>>(frame, dacc);
  k_conv1<<<dim3(4, 126, 4), 256, 0, stream>>>(x, ws, ws + OFF_H);
  k_conv2q<<<dim3(2, 84, 4), 256, 0, stream>>>(ws + OFF_H, ws, dacc,
      fa_wq, fa_bq, bq_c, ws + OFF_Q);
  k_conv2kv<<<dim3(2, 84, 4), 256, 0, stream>>>(ws + OFF_H, frame, ws, dacc,
      fa_wk, fa_bk, fa_wv, fa_bv, bkv_c, Tp, ws + OFF_K, ws + OFF_V);
  k_sink<<<dim3(84, 4), 256, 0, stream>>>(ws + OFF_Q, ws + OFF_K, ws + OFF_SI, dacc);
  k_flow<<<dim3(168, 4), 256, 0, stream>>>(ws + OFF_Q, ws + OFF_K, ws + OFF_V, ws + OFF_SA, dacc);
  k_out<<<dim3(8, 84, 4), 256, 0, stream>>>(ws + OFF_Q, ws + OFF_SI, ws + OFF_SA, dacc,
      fa_wo, fa_bo, out);
}